// Round 7
// baseline (3316.378 us; speedup 1.0000x reference)
//
#include <hip/hip_runtime.h>
#include <hip/hip_bf16.h>

typedef __hip_bfloat16 bf16;
typedef __bf16 v8bf __attribute__((ext_vector_type(8)));
typedef float v4f __attribute__((ext_vector_type(4)));
typedef unsigned short u16x8 __attribute__((ext_vector_type(8)));

// ---------------------------------------------------------------------------
//   x: (8,4096,80) -> conv1(1->128,s2) -> (8,2048,40,128)   [channel-last]
//   -> conv2(128->256,s2) -> halo (8,1026,22,256)           [channel-last+halo]
//   -> conv3(256->512,s1) -> tokens (8,1024,10240)          [token-major]
//   -> embed GEMM (split-K) -> 4 RWKV blocks -> final LN
// GEMM core: bf16 MFMA 16x16x32, TM x 128 tile, BK=32. TM=256 for conv3
// (MFMA density), TM=64 for transformer GEMMs (blocks/CU). LN fused into the
// token-shift mix kernels (predecessor-row LN recomputed in-wave).
// ---------------------------------------------------------------------------

constexpr int B_T = 0, B_CONV = 1;
constexpr int EP_CONV_CL = 0, EP_CONV_T = 1, EP_ATOMIC = 2, EP_KVR = 3,
              EP_ADD = 4, EP_FFN = 5, EP_ADDMUL = 6;

static __device__ __forceinline__ unsigned short f2b(float f) {
    return __builtin_bit_cast(unsigned short, __float2bfloat16(f));
}

// ---------------------------------------------------------------------------
// MFMA GEMM: C[M,N] = A[M,K] * B[K,N]. A bf16 [M][K]; B bf16 [N][K] (B_T) or
// channel-last im2col gather (B_CONV; HALO=1 -> unconditional loads from the
// zero-padded (b,1026,22,256) buffer). ASH>0: A += (n0>>ASH)*M*K (fused ops).
// ---------------------------------------------------------------------------
template <int TM, int BL, int EPM, int ASH, int TIN, int FIN, int STRIDE,
          int ICN, int HALO>
__global__ __launch_bounds__(256) void gemm_k(
    const bf16* __restrict__ A, const bf16* __restrict__ Bw,
    const bf16* __restrict__ Bact,
    float* __restrict__ C, bf16* __restrict__ Cb,
    const float* __restrict__ bias, const float* __restrict__ mul,
    int M, int N, int K, int KLEN)
{
    constexpr int MI = TM / 32;
    __shared__ __align__(16) unsigned short As[TM * 40];
    __shared__ __align__(16) unsigned short Bs[128 * 40];
    const int tid = threadIdx.x;
    const int n0 = blockIdx.x * 128;
    const int m0 = blockIdx.y * TM;
    const int kbase = blockIdx.z * KLEN;
    const int wave = tid >> 6, lane = tid & 63;
    const int wr = wave >> 1, wc = wave & 1;
    const int lq = lane >> 4, lr = lane & 15;

    if constexpr (ASH > 0) A += (size_t)(n0 >> ASH) * M * K;

    v4f acc[MI][4];
#pragma unroll
    for (int i = 0; i < MI; i++)
#pragma unroll
        for (int j = 0; j < 4; j++) acc[i][j] = v4f{0.f, 0.f, 0.f, 0.f};

    int cv_b = 0, cv_to = 0, cv_fo = 0;
    if constexpr (BL == B_CONV) {
        int n = n0 + (tid & 127);
        cv_b = n / 20480;
        int s = n - cv_b * 20480;
        cv_to = s / 20;
        cv_fo = s - cv_to * 20;
    }

    const int a_ml = (tid >> 2), a_kq = (tid & 3) * 8;

    for (int k0 = kbase; k0 < kbase + KLEN; k0 += 32) {
        // ---- stage A: TM x 32 bf16, 16-B loads
#pragma unroll
        for (int i = 0; i < TM / 64; i++) {
            int ml = i * 64 + a_ml;
            *(u16x8*)&As[ml * 40 + a_kq] =
                *(const u16x8*)((const unsigned short*)A + (size_t)(m0 + ml) * K + k0 + a_kq);
        }
        // ---- stage B
        if constexpr (BL == B_T) {
#pragma unroll
            for (int i = 0; i < 2; i++) {
                int nl = i * 64 + a_ml;
                *(u16x8*)&Bs[nl * 40 + a_kq] =
                    *(const u16x8*)((const unsigned short*)Bw + (size_t)(n0 + nl) * K + k0 + a_kq);
            }
        } else {
            int kg = k0 / ICN;             // kt*3+kf
            int ic0 = k0 - kg * ICN;
            int kt = kg / 3, kf = kg - kt * 3;
            int nl = tid & 127;
            int kq = (tid >> 7) * 16;
            if constexpr (HALO) {          // conv3: zero-padded input, no branch
                const unsigned short* src = (const unsigned short*)Bact +
                    (((size_t)cv_b * 1026 + cv_to + kt) * 22 + cv_fo + kf) * 256 + ic0 + kq;
                *(u16x8*)&Bs[nl * 40 + kq] = *(const u16x8*)src;
                *(u16x8*)&Bs[nl * 40 + kq + 8] = *(const u16x8*)(src + 8);
            } else {
                int ti = cv_to * STRIDE - 1 + kt;
                int fi = cv_fo * STRIDE - 1 + kf;
                u16x8 v0 = {0, 0, 0, 0, 0, 0, 0, 0}, v1 = v0;
                if ((unsigned)ti < (unsigned)TIN && (unsigned)fi < (unsigned)FIN) {
                    const unsigned short* src = (const unsigned short*)Bact +
                        (((size_t)cv_b * TIN + ti) * FIN + fi) * ICN + ic0 + kq;
                    v0 = *(const u16x8*)(src);
                    v1 = *(const u16x8*)(src + 8);
                }
                *(u16x8*)&Bs[nl * 40 + kq] = v0;
                *(u16x8*)&Bs[nl * 40 + kq + 8] = v1;
            }
        }
        __syncthreads();

        v8bf fa[MI], fb[4];
#pragma unroll
        for (int mi = 0; mi < MI; mi++)
            fa[mi] = *(const v8bf*)&As[(wr * (TM / 2) + mi * 16 + lr) * 40 + lq * 8];
#pragma unroll
        for (int ni = 0; ni < 4; ni++)
            fb[ni] = *(const v8bf*)&Bs[(wc * 64 + ni * 16 + lr) * 40 + lq * 8];
#pragma unroll
        for (int mi = 0; mi < MI; mi++)
#pragma unroll
            for (int ni = 0; ni < 4; ni++)
                acc[mi][ni] = __builtin_amdgcn_mfma_f32_16x16x32_bf16(
                    fa[mi], fb[ni], acc[mi][ni], 0, 0, 0);
        __syncthreads();
    }

    // ---- epilogue
#pragma unroll
    for (int mi = 0; mi < MI; mi++) {
#pragma unroll
        for (int ni = 0; ni < 4; ni++) {
#pragma unroll
            for (int reg = 0; reg < 4; reg++) {
                int row = m0 + wr * (TM / 2) + mi * 16 + lq * 4 + reg;
                int col = n0 + wc * 64 + ni * 16 + lr;
                float v = acc[mi][ni][reg];
                if constexpr (EPM == EP_CONV_CL) {
                    v += bias[row];
                    v = v > 0.f ? v : 0.f;
                    int b = col / 20480;
                    int s = col - b * 20480;
                    int t = s / 20, fo = s - t * 20;
                    Cb[(((size_t)b * 1026 + t + 1) * 22 + fo + 1) * 256 + row] =
                        __float2bfloat16(v);
                } else if constexpr (EPM == EP_CONV_T) {
                    v += bias[row];
                    v = v > 0.f ? v : 0.f;
                    int b = col / 20480;
                    int s = col - b * 20480;
                    int t = s / 20, fo = s - t * 20;
                    Cb[(size_t)(b * 1024 + t) * 10240 + row * 20 + fo] = __float2bfloat16(v);
                } else if constexpr (EPM == EP_ATOMIC) {
                    float add = (blockIdx.z == 0) ? bias[col] : 0.f;
                    atomicAdd(&C[(size_t)row * N + col], v + add);
                } else if constexpr (EPM == EP_KVR) {
                    int seg = col >> 9;     // 0=k,1=v,2=r (uniform per block)
                    if (seg == 2) v = 1.f / (1.f + __expf(-v));
                    C[(size_t)seg * M * 512 + (size_t)row * 512 + (col & 511)] = v;
                } else if constexpr (EPM == EP_ADD) {
                    C[(size_t)row * N + col] += v;
                } else if constexpr (EPM == EP_FFN) {
                    if (col < 2048) {       // wk branch: sqrelu -> bf16 kkb
                        float t = v > 0.f ? v : 0.f;
                        Cb[(size_t)row * 2048 + col] = __float2bfloat16(t * t);
                    } else {                // wr branch: sigmoid -> f32 rb
                        C[(size_t)row * 512 + (col - 2048)] = 1.f / (1.f + __expf(-v));
                    }
                } else if constexpr (EPM == EP_ADDMUL) {
                    size_t idx = (size_t)row * N + col;
                    C[idx] += mul[idx] * v;
                }
            }
        }
    }
}

// ---------------------------------------------------------------------------
// Prep: conv weight OIHW f32 -> bf16 [oc][(kt*3+kf)*IC + ic]
// ---------------------------------------------------------------------------
__global__ __launch_bounds__(256) void reorder_w_k(const float* __restrict__ in,
                                                   bf16* __restrict__ out,
                                                   int OC, int IC)
{
    int idx = blockIdx.x * 256 + threadIdx.x;
    if (idx >= OC * IC * 9) return;
    int oc = idx / (IC * 9);
    int r = idx - oc * (IC * 9);
    int g = r / IC;
    int ic = r - g * IC;
    out[idx] = __float2bfloat16(in[((size_t)oc * IC + ic) * 9 + g]);
}

// ---------------------------------------------------------------------------
// Prep: f32 [K][N] -> bf16 [N][K]; z: in stride K*N, out stride ozs
// ---------------------------------------------------------------------------
__global__ __launch_bounds__(256) void transpose_k(const float* __restrict__ in,
                                                   bf16* __restrict__ out,
                                                   int K, int N, size_t ozs)
{
    __shared__ float t[32][33];
    const float* pin = in + (size_t)blockIdx.z * K * N;
    bf16* pout = out + (size_t)blockIdx.z * ozs;
    int n0 = blockIdx.x * 32, k0 = blockIdx.y * 32;
    int tx = threadIdx.x & 31, ty = threadIdx.x >> 5;
#pragma unroll
    for (int i = 0; i < 32; i += 8)
        t[ty + i][tx] = pin[(size_t)(k0 + ty + i) * N + n0 + tx];
    __syncthreads();
#pragma unroll
    for (int i = 0; i < 32; i += 8)
        pout[(size_t)(n0 + ty + i) * K + k0 + tx] = __float2bfloat16(t[tx][ty + i]);
}

// ---------------------------------------------------------------------------
// conv1 for a 2-batch chunk: 1 input channel, direct, channel-last output.
// ---------------------------------------------------------------------------
__global__ __launch_bounds__(256) void conv1_k(
    const float* __restrict__ x, const float* __restrict__ w,
    const float* __restrict__ bias, bf16* __restrict__ out)
{
    __shared__ float ws_[128 * 9];
    __shared__ float bs_[128];
    const int tid = threadIdx.x;
    for (int i = tid; i < 128 * 9; i += 256) ws_[i] = w[i];
    if (tid < 128) bs_[tid] = bias[tid];
    __syncthreads();

    int idx = blockIdx.x * 256 + tid;  // 2*2048*40
    int f = idx % 40;
    int t = (idx / 40) & 2047;
    int b = idx / 81920;

    float xin[9];
#pragma unroll
    for (int kt = 0; kt < 3; kt++)
#pragma unroll
        for (int kf = 0; kf < 3; kf++) {
            int ti = 2 * t - 1 + kt, fi = 2 * f - 1 + kf;
            float v = 0.f;
            if ((unsigned)ti < 4096u && (unsigned)fi < 80u)
                v = x[(size_t)b * 327680 + (size_t)ti * 80 + fi];
            xin[kt * 3 + kf] = v;
        }
    unsigned short* outu = (unsigned short*)out + (size_t)idx * 128;
#pragma unroll
    for (int oc8 = 0; oc8 < 16; oc8++) {
        unsigned short pk[8];
#pragma unroll
        for (int j = 0; j < 8; j++) {
            int oc = oc8 * 8 + j;
            float a = bs_[oc];
#pragma unroll
            for (int q = 0; q < 9; q++) a += ws_[oc * 9 + q] * xin[q];
            a = a > 0.f ? a : 0.f;
            pk[j] = f2b(a);
        }
        *(u16x8*)&outu[oc8 * 8] = *(u16x8*)pk;
    }
}

// ---------------------------------------------------------------------------
// LayerNorm over D=512, one wave per row (4 rows / block)
// ---------------------------------------------------------------------------
__global__ __launch_bounds__(256) void ln_k(
    const float* __restrict__ in, float* __restrict__ out,
    const float* __restrict__ g, const float* __restrict__ b, int M)
{
    int wave = threadIdx.x >> 6;
    int lane = threadIdx.x & 63;
    int row = blockIdx.x * 4 + wave;
    if (row >= M) return;
    const float* p = in + (size_t)row * 512;
    float v[8], s = 0.f, sq = 0.f;
#pragma unroll
    for (int i = 0; i < 8; i++) {
        v[i] = p[lane + i * 64];
        s += v[i];
        sq += v[i] * v[i];
    }
#pragma unroll
    for (int o = 32; o > 0; o >>= 1) {
        s += __shfl_xor(s, o, 64);
        sq += __shfl_xor(sq, o, 64);
    }
    float mean = s * (1.f / 512.f);
    float var = sq * (1.f / 512.f) - mean * mean;
    float r = rsqrtf(var + 1e-5f);
    float* q = out + (size_t)row * 512;
#pragma unroll
    for (int i = 0; i < 8; i++) {
        int d = lane + i * 64;
        q[d] = (v[i] - mean) * r * g[d] + b[d];
    }
}

// ---------------------------------------------------------------------------
// Fused LN + token-shift mix -> bf16 operands. One wave per row; the wave
// also recomputes the predecessor row's LN (exact same f32 math). Lane owns
// 8 contiguous dims (16-B loads/stores). NOUT=3 (att) or 2 (ffn).
// ---------------------------------------------------------------------------
template <int NOUT>
__global__ __launch_bounds__(256) void lnmix_k(
    const float* __restrict__ hb, const float* __restrict__ g,
    const float* __restrict__ b, const float* __restrict__ mk,
    const float* __restrict__ mv, const float* __restrict__ mr,
    bf16* __restrict__ ok, bf16* __restrict__ ov, bf16* __restrict__ orr)
{
    int wave = threadIdx.x >> 6, lane = threadIdx.x & 63;
    int row = blockIdx.x * 4 + wave;     // 8192 rows
    int u = row & 1023;
    int d0 = lane * 8;
    const float* pc = hb + (size_t)row * 512 + d0;

    float vc[8], vp[8];
    *(float4*)&vc[0] = *(const float4*)pc;
    *(float4*)&vc[4] = *(const float4*)(pc + 4);
    float s = 0.f, sq = 0.f, sp = 0.f, sqp = 0.f;
#pragma unroll
    for (int i = 0; i < 8; i++) { s += vc[i]; sq += vc[i] * vc[i]; }
    if (u) {
        *(float4*)&vp[0] = *(const float4*)(pc - 512);
        *(float4*)&vp[4] = *(const float4*)(pc - 508);
#pragma unroll
        for (int i = 0; i < 8; i++) { sp += vp[i]; sqp += vp[i] * vp[i]; }
    } else {
#pragma unroll
        for (int i = 0; i < 8; i++) vp[i] = 0.f;
    }
#pragma unroll
    for (int o = 32; o > 0; o >>= 1) {
        s += __shfl_xor(s, o, 64);
        sq += __shfl_xor(sq, o, 64);
        sp += __shfl_xor(sp, o, 64);
        sqp += __shfl_xor(sqp, o, 64);
    }
    float mc = s * (1.f / 512.f);
    float rc = rsqrtf(sq * (1.f / 512.f) - mc * mc + 1e-5f);
    float mp = sp * (1.f / 512.f);
    float rp = rsqrtf(sqp * (1.f / 512.f) - mp * mp + 1e-5f);

    float gv[8], bv[8], xc[8], xp[8];
    *(float4*)&gv[0] = *(const float4*)(g + d0);
    *(float4*)&gv[4] = *(const float4*)(g + d0 + 4);
    *(float4*)&bv[0] = *(const float4*)(b + d0);
    *(float4*)&bv[4] = *(const float4*)(b + d0 + 4);
#pragma unroll
    for (int i = 0; i < 8; i++) {
        xc[i] = (vc[i] - mc) * rc * gv[i] + bv[i];
        xp[i] = u ? (vp[i] - mp) * rp * gv[i] + bv[i] : 0.f;
    }

    size_t ob = (size_t)row * 512 + d0;
    float a[8];
    unsigned short o16[8];
    *(float4*)&a[0] = *(const float4*)(mk + d0);
    *(float4*)&a[4] = *(const float4*)(mk + d0 + 4);
#pragma unroll
    for (int i = 0; i < 8; i++) o16[i] = f2b(xc[i] * a[i] + xp[i] * (1.f - a[i]));
    *(u16x8*)((unsigned short*)ok + ob) = *(u16x8*)o16;
    if constexpr (NOUT == 3) {
        *(float4*)&a[0] = *(const float4*)(mv + d0);
        *(float4*)&a[4] = *(const float4*)(mv + d0 + 4);
#pragma unroll
        for (int i = 0; i < 8; i++) o16[i] = f2b(xc[i] * a[i] + xp[i] * (1.f - a[i]));
        *(u16x8*)((unsigned short*)ov + ob) = *(u16x8*)o16;
    }
    *(float4*)&a[0] = *(const float4*)(mr + d0);
    *(float4*)&a[4] = *(const float4*)(mr + d0 + 4);
#pragma unroll
    for (int i = 0; i < 8; i++) o16[i] = f2b(xc[i] * a[i] + xp[i] * (1.f - a[i]));
    *(u16x8*)((unsigned short*)orr + ob) = *(u16x8*)o16;
}

// ---------------------------------------------------------------------------
// WKV sequential scan; one thread per (b,d); 4-step software pipeline
// (12 independent loads in flight per 4 compute steps). out = bf16(r*wkv).
// ---------------------------------------------------------------------------
__global__ __launch_bounds__(64) void wkv_k(
    const float* __restrict__ kbuf, const float* __restrict__ vbuf,
    const float* __restrict__ rbuf, bf16* __restrict__ outbuf,
    const float* __restrict__ decay, const float* __restrict__ first)
{
    int idx = blockIdx.x * 64 + threadIdx.x;
    int d = idx & 511;
    int b = idx >> 9;
    float w = -__expf(decay[d]);
    float u = first[d];
    float aa = 0.f, bb = 0.f, pp = -1e38f;
    size_t base = (size_t)b * 1024 * 512 + d;
    float kc[4], vc[4], rc[4];
#pragma unroll
    for (int j = 0; j < 4; j++) {
        kc[j] = kbuf[base + (size_t)j * 512];
        vc[j] = vbuf[base + (size_t)j * 512];
        rc[j] = rbuf[base + (size_t)j * 512];
    }
    for (int t = 0; t < 1024; t += 4) {
        float kn[4] = {0, 0, 0, 0}, vn[4] = {0, 0, 0, 0}, rn[4] = {0, 0, 0, 0};
        if (t + 4 < 1024) {
            size_t nb = base + (size_t)(t + 4) * 512;
#pragma unroll
            for (int j = 0; j < 4; j++) {
                kn[j] = kbuf[nb + (size_t)j * 512];
                vn[j] = vbuf[nb + (size_t)j * 512];
                rn[j] = rbuf[nb + (size_t)j * 512];
            }
        }
#pragma unroll
        for (int j = 0; j < 4; j++) {
            float kt = kc[j], vt = vc[j], rt = rc[j];
            float ww = u + kt;
            float p = pp > ww ? pp : ww;
            float e1 = __expf(pp - p), e2 = __expf(ww - p);
            float out = (e1 * aa + e2 * vt) / (e1 * bb + e2);
            outbuf[base + (size_t)(t + j) * 512] = __float2bfloat16(rt * out);
            float ww2 = pp + w;
            float p2 = ww2 > kt ? ww2 : kt;
            e1 = __expf(ww2 - p2);
            e2 = __expf(kt - p2);
            aa = e1 * aa + e2 * vt;
            bb = e1 * bb + e2;
            pp = p2;
        }
#pragma unroll
        for (int j = 0; j < 4; j++) { kc[j] = kn[j]; vc[j] = vn[j]; rc[j] = rn[j]; }
    }
}

__global__ void olens_k(const int* __restrict__ x_len, float* __restrict__ out)
{
    int i = threadIdx.x;
    if (i < 8) {
        int l1 = (x_len[i] - 1) / 2 + 1;
        int ol = (l1 - 1) / 2 + 1;
        out[i] = (float)ol;
    }
}

// ---------------------------------------------------------------------------
extern "C" void kernel_launch(void* const* d_in, const int* in_sizes, int n_in,
                              void* d_out, int out_size, void* d_ws, size_t ws_size,
                              hipStream_t stream)
{
    (void)in_sizes; (void)n_in; (void)out_size; (void)ws_size;
    const float* x         = (const float*)d_in[0];
    const int*   x_len     = (const int*)d_in[1];
    const float* conv1_w   = (const float*)d_in[2];
    const float* conv1_b   = (const float*)d_in[3];
    const float* conv2_w   = (const float*)d_in[4];
    const float* conv2_b   = (const float*)d_in[5];
    const float* conv3_w   = (const float*)d_in[6];
    const float* conv3_b   = (const float*)d_in[7];
    const float* embed_w   = (const float*)d_in[8];
    const float* embed_b   = (const float*)d_in[9];
    const float* embed_ln_g= (const float*)d_in[10];
    const float* embed_ln_b= (const float*)d_in[11];
    const float* ln_att_g  = (const float*)d_in[12];
    const float* ln_att_b  = (const float*)d_in[13];
    const float* att_decay = (const float*)d_in[14];
    const float* att_first = (const float*)d_in[15];
    const float* att_mix_k = (const float*)d_in[16];
    const float* att_mix_v = (const float*)d_in[17];
    const float* att_mix_r = (const float*)d_in[18];
    const float* att_wk    = (const float*)d_in[19];
    const float* att_wv    = (const float*)d_in[20];
    const float* att_wr    = (const float*)d_in[21];
    const float* att_wo    = (const float*)d_in[22];
    const float* ln_ffn_g  = (const float*)d_in[23];
    const float* ln_ffn_b  = (const float*)d_in[24];
    const float* ffn_mix_k = (const float*)d_in[25];
    const float* ffn_mix_r = (const float*)d_in[26];
    const float* ffn_wk    = (const float*)d_in[27];
    const float* ffn_wv    = (const float*)d_in[28];
    const float* ffn_wr    = (const float*)d_in[29];
    const float* final_ln_g= (const float*)d_in[30];
    const float* final_ln_b= (const float*)d_in[31];

    // ---- workspace layout (MiB offsets, ~183 MiB) ----
    // 0..16 h | 16..32 xn | 32..40 rwkvb | 40..64 xkvr (xf aliases 40..56)
    // 64..112 kvrb | 112..144 kkb
    // conv overlay: c1b 40..80 | c2b(halo) 80..102.1 | c3b 104..144
    // weights: attT 144..150 | attTo 150..152 | ffnT 152..162 | ffnTv 162..170
    //          embT 170..180 | c2wb 180..180.6 | c3wb 180.6..182.9
    char* wsb = (char*)d_ws;
    float* h     = (float*)(wsb);
    float* xn    = (float*)(wsb + (16LL << 20));
    bf16*  rwkvb = (bf16*) (wsb + (32LL << 20));
    bf16*  xkvr  = (bf16*) (wsb + (40LL << 20));   // [3][8192][512] bf16
    bf16*  xf    = xkvr;                           // [2][8192][512] bf16 (ffn)
    float* kvrb  = (float*)(wsb + (64LL << 20));   // [3][8192][512] f32
    bf16*  kkb   = (bf16*) (wsb + (112LL << 20));  // [8192][2048] bf16
    bf16*  c1b   = (bf16*) (wsb + (40LL << 20));   // (2,2048,40,128)
    bf16*  c2b   = (bf16*) (wsb + (80LL << 20));   // (2,1026,22,256) halo
    bf16*  c3b   = (bf16*) (wsb + (104LL << 20));  // (2048,10240)
    bf16*  attT  = (bf16*) (wsb + (144LL << 20));  // 4 x [1536][512] (k,v,r)
    bf16*  attTo = (bf16*) (wsb + (150LL << 20));  // 4 x [512][512]  (wo)
    bf16*  ffnT  = (bf16*) (wsb + (152LL << 20));  // 4 x [2560][512] (wk|wr)
    bf16*  ffnTv = (bf16*) (wsb + (162LL << 20));  // 4 x [512][2048]
    bf16*  embT  = (bf16*) (wsb + (170LL << 20));  // [512][10240]
    bf16*  c2wb  = (bf16*) (wsb + (180LL << 20));  // 256 x 1152
    bf16*  c3wb  = (bf16*) (wsb + (180LL << 20) + 589824);  // 512 x 2304

    const size_t MD = 8192LL * 512;

    // ---- weight prep: packed transposed bf16
    transpose_k<<<dim3(16, 16, 4), 256, 0, stream>>>(att_wk, attT, 512, 512, 786432);
    transpose_k<<<dim3(16, 16, 4), 256, 0, stream>>>(att_wv, attT + 262144, 512, 512, 786432);
    transpose_k<<<dim3(16, 16, 4), 256, 0, stream>>>(att_wr, attT + 524288, 512, 512, 786432);
    transpose_k<<<dim3(16, 16, 4), 256, 0, stream>>>(att_wo, attTo, 512, 512, 262144);
    transpose_k<<<dim3(64, 16, 4), 256, 0, stream>>>(ffn_wk, ffnT, 512, 2048, 1310720);
    transpose_k<<<dim3(16, 16, 4), 256, 0, stream>>>(ffn_wr, ffnT + 1048576, 512, 512, 1310720);
    transpose_k<<<dim3(16, 64, 4), 256, 0, stream>>>(ffn_wv, ffnTv, 2048, 512, 1048576);
    transpose_k<<<dim3(16, 320, 1), 256, 0, stream>>>(embed_w, embT, 10240, 512, 0);
    reorder_w_k<<<1152, 256, 0, stream>>>(conv2_w, c2wb, 256, 128);
    reorder_w_k<<<4608, 256, 0, stream>>>(conv3_w, c3wb, 512, 256);
    hipMemsetAsync(xn, 0, 16LL << 20, stream);
    hipMemsetAsync(c2b, 0, 2LL * 1026 * 22 * 256 * 2, stream);

    // ---- conv frontend + embed (split-K x4, atomic), 2 batches per chunk
    for (int chunk = 0; chunk < 4; chunk++) {
        int b0 = chunk * 2;
        conv1_k<<<640, 256, 0, stream>>>(x + (size_t)b0 * 327680, conv1_w, conv1_b, c1b);
        gemm_k<128, B_CONV, EP_CONV_CL, 0, 2048, 40, 2, 128, 0><<<dim3(320, 2), 256, 0, stream>>>(
            c2wb, nullptr, c1b, nullptr, c2b, conv2_b, nullptr, 256, 40960, 1152, 1152);
        gemm_k<256, B_CONV, EP_CONV_T, 0, 1024, 20, 1, 256, 1><<<dim3(320, 2), 256, 0, stream>>>(
            c3wb, nullptr, c2b, nullptr, c3b, conv3_b, nullptr, 512, 40960, 2304, 2304);
        gemm_k<64, B_T, EP_ATOMIC, 0, 0, 0, 0, 0, 0><<<dim3(4, 32, 4), 256, 0, stream>>>(
            c3b, embT, nullptr, xn + (size_t)b0 * 1024 * 512, nullptr, embed_b, nullptr,
            2048, 512, 10240, 2560);
    }
    ln_k<<<2048, 256, 0, stream>>>(xn, h, embed_ln_g, embed_ln_b, 8192);

    // ---- 4 RWKV blocks
    for (int i = 0; i < 4; i++) {
        // time mixing (LN fused into mix)
        lnmix_k<3><<<2048, 256, 0, stream>>>(h, ln_att_g + i * 512, ln_att_b + i * 512,
                                             att_mix_k + i * 512, att_mix_v + i * 512,
                                             att_mix_r + i * 512,
                                             xkvr, xkvr + MD, xkvr + 2 * MD);
        gemm_k<64, B_T, EP_KVR, 9, 0, 0, 0, 0, 0><<<dim3(12, 128), 256, 0, stream>>>(
            xkvr, attT + (size_t)i * 786432, nullptr, kvrb, nullptr, nullptr, nullptr,
            8192, 1536, 512, 512);
        wkv_k<<<64, 64, 0, stream>>>(kvrb, kvrb + MD, kvrb + 2 * MD, rwkvb,
                                     att_decay + i * 512, att_first + i * 512);
        gemm_k<64, B_T, EP_ADD, 0, 0, 0, 0, 0, 0><<<dim3(4, 128), 256, 0, stream>>>(
            rwkvb, attTo + (size_t)i * 262144, nullptr, h, nullptr, nullptr, nullptr,
            8192, 512, 512, 512);
        // channel mixing (LN fused into mix)
        lnmix_k<2><<<2048, 256, 0, stream>>>(h, ln_ffn_g + i * 512, ln_ffn_b + i * 512,
                                             ffn_mix_k + i * 512, nullptr,
                                             ffn_mix_r + i * 512,
                                             xf, nullptr, xf + MD);
        gemm_k<64, B_T, EP_FFN, 11, 0, 0, 0, 0, 0><<<dim3(20, 128), 256, 0, stream>>>(
            xf, ffnT + (size_t)i * 1310720, nullptr, kvrb + 2 * MD, kkb, nullptr, nullptr,
            8192, 2560, 512, 512);
        gemm_k<64, B_T, EP_ADDMUL, 0, 0, 0, 0, 0, 0><<<dim3(4, 128), 256, 0, stream>>>(
            kkb, ffnTv + (size_t)i * 1048576, nullptr, h, nullptr, nullptr, kvrb + 2 * MD,
            8192, 512, 2048, 2048);
    }

    // ---- final LN straight into d_out, then olens
    ln_k<<<2048, 256, 0, stream>>>(h, (float*)d_out, final_ln_g, final_ln_b, 8192);
    olens_k<<<1, 64, 0, stream>>>(x_len, (float*)d_out + 4194304);
}

// Round 8
// 2774.311 us; speedup vs baseline: 1.1954x; 1.1954x over previous
//
#include <hip/hip_runtime.h>
#include <hip/hip_bf16.h>

typedef __hip_bfloat16 bf16;
typedef __bf16 v8bf __attribute__((ext_vector_type(8)));
typedef float v4f __attribute__((ext_vector_type(4)));
typedef unsigned short u16x8 __attribute__((ext_vector_type(8)));

// ---------------------------------------------------------------------------
//   x: (8,4096,80) -> conv1(1->128,s2) -> (8,2048,40,128)   [channel-last]
//   -> conv2(128->256,s2) -> halo (8,1026,22,256)           [channel-last+halo]
//   -> conv3(256->512,s1) -> tokens (8,1024,10240)          [token-major]
//   -> embed GEMM (split-K) -> 4 RWKV blocks -> final LN
// GEMM core: bf16 MFMA 16x16x32, TM x 128 tile, BK=32. TM=128 for convs
// (TM=256 measured WORSE: occupancy 27%->10%, MfmaUtil 23%->12%, r7),
// TM=64 for transformer GEMMs (blocks/CU). LN fused into token-shift mix.
// ---------------------------------------------------------------------------

constexpr int B_T = 0, B_CONV = 1;
constexpr int EP_CONV_CL = 0, EP_CONV_T = 1, EP_ATOMIC = 2, EP_KVR = 3,
              EP_ADD = 4, EP_FFN = 5, EP_ADDMUL = 6;

static __device__ __forceinline__ unsigned short f2b(float f) {
    return __builtin_bit_cast(unsigned short, __float2bfloat16(f));
}

// ---------------------------------------------------------------------------
// MFMA GEMM: C[M,N] = A[M,K] * B[K,N]. A bf16 [M][K]; B bf16 [N][K] (B_T) or
// channel-last im2col gather (B_CONV; HALO=1 -> unconditional loads from the
// zero-padded (b,1026,22,256) buffer). ASH>0: A += (n0>>ASH)*M*K (fused ops).
// ---------------------------------------------------------------------------
template <int TM, int BL, int EPM, int ASH, int TIN, int FIN, int STRIDE,
          int ICN, int HALO>
__global__ __launch_bounds__(256) void gemm_k(
    const bf16* __restrict__ A, const bf16* __restrict__ Bw,
    const bf16* __restrict__ Bact,
    float* __restrict__ C, bf16* __restrict__ Cb,
    const float* __restrict__ bias, const float* __restrict__ mul,
    int M, int N, int K, int KLEN)
{
    constexpr int MI = TM / 32;
    __shared__ __align__(16) unsigned short As[TM * 40];
    __shared__ __align__(16) unsigned short Bs[128 * 40];
    const int tid = threadIdx.x;
    const int n0 = blockIdx.x * 128;
    const int m0 = blockIdx.y * TM;
    const int kbase = blockIdx.z * KLEN;
    const int wave = tid >> 6, lane = tid & 63;
    const int wr = wave >> 1, wc = wave & 1;
    const int lq = lane >> 4, lr = lane & 15;

    if constexpr (ASH > 0) A += (size_t)(n0 >> ASH) * M * K;

    v4f acc[MI][4];
#pragma unroll
    for (int i = 0; i < MI; i++)
#pragma unroll
        for (int j = 0; j < 4; j++) acc[i][j] = v4f{0.f, 0.f, 0.f, 0.f};

    int cv_b = 0, cv_to = 0, cv_fo = 0;
    if constexpr (BL == B_CONV) {
        int n = n0 + (tid & 127);
        cv_b = n / 20480;
        int s = n - cv_b * 20480;
        cv_to = s / 20;
        cv_fo = s - cv_to * 20;
    }

    const int a_ml = (tid >> 2), a_kq = (tid & 3) * 8;

    for (int k0 = kbase; k0 < kbase + KLEN; k0 += 32) {
        // ---- stage A: TM x 32 bf16, 16-B loads
#pragma unroll
        for (int i = 0; i < TM / 64; i++) {
            int ml = i * 64 + a_ml;
            *(u16x8*)&As[ml * 40 + a_kq] =
                *(const u16x8*)((const unsigned short*)A + (size_t)(m0 + ml) * K + k0 + a_kq);
        }
        // ---- stage B
        if constexpr (BL == B_T) {
#pragma unroll
            for (int i = 0; i < 2; i++) {
                int nl = i * 64 + a_ml;
                *(u16x8*)&Bs[nl * 40 + a_kq] =
                    *(const u16x8*)((const unsigned short*)Bw + (size_t)(n0 + nl) * K + k0 + a_kq);
            }
        } else {
            int kg = k0 / ICN;             // kt*3+kf
            int ic0 = k0 - kg * ICN;
            int kt = kg / 3, kf = kg - kt * 3;
            int nl = tid & 127;
            int kq = (tid >> 7) * 16;
            if constexpr (HALO) {          // conv3: zero-padded input, no branch
                const unsigned short* src = (const unsigned short*)Bact +
                    (((size_t)cv_b * 1026 + cv_to + kt) * 22 + cv_fo + kf) * 256 + ic0 + kq;
                *(u16x8*)&Bs[nl * 40 + kq] = *(const u16x8*)src;
                *(u16x8*)&Bs[nl * 40 + kq + 8] = *(const u16x8*)(src + 8);
            } else {
                int ti = cv_to * STRIDE - 1 + kt;
                int fi = cv_fo * STRIDE - 1 + kf;
                u16x8 v0 = {0, 0, 0, 0, 0, 0, 0, 0}, v1 = v0;
                if ((unsigned)ti < (unsigned)TIN && (unsigned)fi < (unsigned)FIN) {
                    const unsigned short* src = (const unsigned short*)Bact +
                        (((size_t)cv_b * TIN + ti) * FIN + fi) * ICN + ic0 + kq;
                    v0 = *(const u16x8*)(src);
                    v1 = *(const u16x8*)(src + 8);
                }
                *(u16x8*)&Bs[nl * 40 + kq] = v0;
                *(u16x8*)&Bs[nl * 40 + kq + 8] = v1;
            }
        }
        __syncthreads();

        v8bf fa[MI], fb[4];
#pragma unroll
        for (int mi = 0; mi < MI; mi++)
            fa[mi] = *(const v8bf*)&As[(wr * (TM / 2) + mi * 16 + lr) * 40 + lq * 8];
#pragma unroll
        for (int ni = 0; ni < 4; ni++)
            fb[ni] = *(const v8bf*)&Bs[(wc * 64 + ni * 16 + lr) * 40 + lq * 8];
#pragma unroll
        for (int mi = 0; mi < MI; mi++)
#pragma unroll
            for (int ni = 0; ni < 4; ni++)
                acc[mi][ni] = __builtin_amdgcn_mfma_f32_16x16x32_bf16(
                    fa[mi], fb[ni], acc[mi][ni], 0, 0, 0);
        __syncthreads();
    }

    // ---- epilogue
#pragma unroll
    for (int mi = 0; mi < MI; mi++) {
#pragma unroll
        for (int ni = 0; ni < 4; ni++) {
#pragma unroll
            for (int reg = 0; reg < 4; reg++) {
                int row = m0 + wr * (TM / 2) + mi * 16 + lq * 4 + reg;
                int col = n0 + wc * 64 + ni * 16 + lr;
                float v = acc[mi][ni][reg];
                if constexpr (EPM == EP_CONV_CL) {
                    v += bias[row];
                    v = v > 0.f ? v : 0.f;
                    int b = col / 20480;
                    int s = col - b * 20480;
                    int t = s / 20, fo = s - t * 20;
                    Cb[(((size_t)b * 1026 + t + 1) * 22 + fo + 1) * 256 + row] =
                        __float2bfloat16(v);
                } else if constexpr (EPM == EP_CONV_T) {
                    v += bias[row];
                    v = v > 0.f ? v : 0.f;
                    int b = col / 20480;
                    int s = col - b * 20480;
                    int t = s / 20, fo = s - t * 20;
                    Cb[(size_t)(b * 1024 + t) * 10240 + row * 20 + fo] = __float2bfloat16(v);
                } else if constexpr (EPM == EP_ATOMIC) {
                    float add = (blockIdx.z == 0) ? bias[col] : 0.f;
                    atomicAdd(&C[(size_t)row * N + col], v + add);
                } else if constexpr (EPM == EP_KVR) {
                    int seg = col >> 9;     // 0=k,1=v,2=r (uniform per block)
                    if (seg == 2) v = 1.f / (1.f + __expf(-v));
                    C[(size_t)seg * M * 512 + (size_t)row * 512 + (col & 511)] = v;
                } else if constexpr (EPM == EP_ADD) {
                    C[(size_t)row * N + col] += v;
                } else if constexpr (EPM == EP_FFN) {
                    if (col < 2048) {       // wk branch: sqrelu -> bf16 kkb
                        float t = v > 0.f ? v : 0.f;
                        Cb[(size_t)row * 2048 + col] = __float2bfloat16(t * t);
                    } else {                // wr branch: sigmoid -> f32 rb
                        C[(size_t)row * 512 + (col - 2048)] = 1.f / (1.f + __expf(-v));
                    }
                } else if constexpr (EPM == EP_ADDMUL) {
                    size_t idx = (size_t)row * N + col;
                    C[idx] += mul[idx] * v;
                }
            }
        }
    }
}

// ---------------------------------------------------------------------------
// Prep: conv weight OIHW f32 -> bf16 [oc][(kt*3+kf)*IC + ic]
// ---------------------------------------------------------------------------
__global__ __launch_bounds__(256) void reorder_w_k(const float* __restrict__ in,
                                                   bf16* __restrict__ out,
                                                   int OC, int IC)
{
    int idx = blockIdx.x * 256 + threadIdx.x;
    if (idx >= OC * IC * 9) return;
    int oc = idx / (IC * 9);
    int r = idx - oc * (IC * 9);
    int g = r / IC;
    int ic = r - g * IC;
    out[idx] = __float2bfloat16(in[((size_t)oc * IC + ic) * 9 + g]);
}

// ---------------------------------------------------------------------------
// Prep: f32 [K][N] -> bf16 [N][K]; z: in stride K*N, out stride ozs
// ---------------------------------------------------------------------------
__global__ __launch_bounds__(256) void transpose_k(const float* __restrict__ in,
                                                   bf16* __restrict__ out,
                                                   int K, int N, size_t ozs)
{
    __shared__ float t[32][33];
    const float* pin = in + (size_t)blockIdx.z * K * N;
    bf16* pout = out + (size_t)blockIdx.z * ozs;
    int n0 = blockIdx.x * 32, k0 = blockIdx.y * 32;
    int tx = threadIdx.x & 31, ty = threadIdx.x >> 5;
#pragma unroll
    for (int i = 0; i < 32; i += 8)
        t[ty + i][tx] = pin[(size_t)(k0 + ty + i) * N + n0 + tx];
    __syncthreads();
#pragma unroll
    for (int i = 0; i < 32; i += 8)
        pout[(size_t)(n0 + ty + i) * K + k0 + tx] = __float2bfloat16(t[tx][ty + i]);
}

// ---------------------------------------------------------------------------
// conv1 for a 2-batch chunk: 1 input channel, direct, channel-last output.
// ---------------------------------------------------------------------------
__global__ __launch_bounds__(256) void conv1_k(
    const float* __restrict__ x, const float* __restrict__ w,
    const float* __restrict__ bias, bf16* __restrict__ out)
{
    __shared__ float ws_[128 * 9];
    __shared__ float bs_[128];
    const int tid = threadIdx.x;
    for (int i = tid; i < 128 * 9; i += 256) ws_[i] = w[i];
    if (tid < 128) bs_[tid] = bias[tid];
    __syncthreads();

    int idx = blockIdx.x * 256 + tid;  // 2*2048*40
    int f = idx % 40;
    int t = (idx / 40) & 2047;
    int b = idx / 81920;

    float xin[9];
#pragma unroll
    for (int kt = 0; kt < 3; kt++)
#pragma unroll
        for (int kf = 0; kf < 3; kf++) {
            int ti = 2 * t - 1 + kt, fi = 2 * f - 1 + kf;
            float v = 0.f;
            if ((unsigned)ti < 4096u && (unsigned)fi < 80u)
                v = x[(size_t)b * 327680 + (size_t)ti * 80 + fi];
            xin[kt * 3 + kf] = v;
        }
    unsigned short* outu = (unsigned short*)out + (size_t)idx * 128;
#pragma unroll
    for (int oc8 = 0; oc8 < 16; oc8++) {
        unsigned short pk[8];
#pragma unroll
        for (int j = 0; j < 8; j++) {
            int oc = oc8 * 8 + j;
            float a = bs_[oc];
#pragma unroll
            for (int q = 0; q < 9; q++) a += ws_[oc * 9 + q] * xin[q];
            a = a > 0.f ? a : 0.f;
            pk[j] = f2b(a);
        }
        *(u16x8*)&outu[oc8 * 8] = *(u16x8*)pk;
    }
}

// ---------------------------------------------------------------------------
// LayerNorm over D=512, one wave per row (4 rows / block)
// ---------------------------------------------------------------------------
__global__ __launch_bounds__(256) void ln_k(
    const float* __restrict__ in, float* __restrict__ out,
    const float* __restrict__ g, const float* __restrict__ b, int M)
{
    int wave = threadIdx.x >> 6;
    int lane = threadIdx.x & 63;
    int row = blockIdx.x * 4 + wave;
    if (row >= M) return;
    const float* p = in + (size_t)row * 512;
    float v[8], s = 0.f, sq = 0.f;
#pragma unroll
    for (int i = 0; i < 8; i++) {
        v[i] = p[lane + i * 64];
        s += v[i];
        sq += v[i] * v[i];
    }
#pragma unroll
    for (int o = 32; o > 0; o >>= 1) {
        s += __shfl_xor(s, o, 64);
        sq += __shfl_xor(sq, o, 64);
    }
    float mean = s * (1.f / 512.f);
    float var = sq * (1.f / 512.f) - mean * mean;
    float r = rsqrtf(var + 1e-5f);
    float* q = out + (size_t)row * 512;
#pragma unroll
    for (int i = 0; i < 8; i++) {
        int d = lane + i * 64;
        q[d] = (v[i] - mean) * r * g[d] + b[d];
    }
}

// ---------------------------------------------------------------------------
// Fused LN + token-shift mix -> bf16 operands. One wave per row; the wave
// also recomputes the predecessor row's LN (exact same f32 math). Lane owns
// 8 contiguous dims (16-B loads/stores). NOUT=3 (att) or 2 (ffn).
// ---------------------------------------------------------------------------
template <int NOUT>
__global__ __launch_bounds__(256) void lnmix_k(
    const float* __restrict__ hb, const float* __restrict__ g,
    const float* __restrict__ b, const float* __restrict__ mk,
    const float* __restrict__ mv, const float* __restrict__ mr,
    bf16* __restrict__ ok, bf16* __restrict__ ov, bf16* __restrict__ orr)
{
    int wave = threadIdx.x >> 6, lane = threadIdx.x & 63;
    int row = blockIdx.x * 4 + wave;     // 8192 rows
    int u = row & 1023;
    int d0 = lane * 8;
    const float* pc = hb + (size_t)row * 512 + d0;

    float vc[8], vp[8];
    *(float4*)&vc[0] = *(const float4*)pc;
    *(float4*)&vc[4] = *(const float4*)(pc + 4);
    float s = 0.f, sq = 0.f, sp = 0.f, sqp = 0.f;
#pragma unroll
    for (int i = 0; i < 8; i++) { s += vc[i]; sq += vc[i] * vc[i]; }
    if (u) {
        *(float4*)&vp[0] = *(const float4*)(pc - 512);
        *(float4*)&vp[4] = *(const float4*)(pc - 508);
#pragma unroll
        for (int i = 0; i < 8; i++) { sp += vp[i]; sqp += vp[i] * vp[i]; }
    } else {
#pragma unroll
        for (int i = 0; i < 8; i++) vp[i] = 0.f;
    }
#pragma unroll
    for (int o = 32; o > 0; o >>= 1) {
        s += __shfl_xor(s, o, 64);
        sq += __shfl_xor(sq, o, 64);
        sp += __shfl_xor(sp, o, 64);
        sqp += __shfl_xor(sqp, o, 64);
    }
    float mc = s * (1.f / 512.f);
    float rc = rsqrtf(sq * (1.f / 512.f) - mc * mc + 1e-5f);
    float mp = sp * (1.f / 512.f);
    float rp = rsqrtf(sqp * (1.f / 512.f) - mp * mp + 1e-5f);

    float gv[8], bv[8], xc[8], xp[8];
    *(float4*)&gv[0] = *(const float4*)(g + d0);
    *(float4*)&gv[4] = *(const float4*)(g + d0 + 4);
    *(float4*)&bv[0] = *(const float4*)(b + d0);
    *(float4*)&bv[4] = *(const float4*)(b + d0 + 4);
#pragma unroll
    for (int i = 0; i < 8; i++) {
        xc[i] = (vc[i] - mc) * rc * gv[i] + bv[i];
        xp[i] = u ? (vp[i] - mp) * rp * gv[i] + bv[i] : 0.f;
    }

    size_t ob = (size_t)row * 512 + d0;
    float a[8];
    unsigned short o16[8];
    *(float4*)&a[0] = *(const float4*)(mk + d0);
    *(float4*)&a[4] = *(const float4*)(mk + d0 + 4);
#pragma unroll
    for (int i = 0; i < 8; i++) o16[i] = f2b(xc[i] * a[i] + xp[i] * (1.f - a[i]));
    *(u16x8*)((unsigned short*)ok + ob) = *(u16x8*)o16;
    if constexpr (NOUT == 3) {
        *(float4*)&a[0] = *(const float4*)(mv + d0);
        *(float4*)&a[4] = *(const float4*)(mv + d0 + 4);
#pragma unroll
        for (int i = 0; i < 8; i++) o16[i] = f2b(xc[i] * a[i] + xp[i] * (1.f - a[i]));
        *(u16x8*)((unsigned short*)ov + ob) = *(u16x8*)o16;
    }
    *(float4*)&a[0] = *(const float4*)(mr + d0);
    *(float4*)&a[4] = *(const float4*)(mr + d0 + 4);
#pragma unroll
    for (int i = 0; i < 8; i++) o16[i] = f2b(xc[i] * a[i] + xp[i] * (1.f - a[i]));
    *(u16x8*)((unsigned short*)orr + ob) = *(u16x8*)o16;
}

// ---------------------------------------------------------------------------
// WKV sequential scan; one thread per (b,d); 4-step software pipeline
// (12 independent loads in flight per 4 compute steps). out = bf16(r*wkv).
// ---------------------------------------------------------------------------
__global__ __launch_bounds__(64) void wkv_k(
    const float* __restrict__ kbuf, const float* __restrict__ vbuf,
    const float* __restrict__ rbuf, bf16* __restrict__ outbuf,
    const float* __restrict__ decay, const float* __restrict__ first)
{
    int idx = blockIdx.x * 64 + threadIdx.x;
    int d = idx & 511;
    int b = idx >> 9;
    float w = -__expf(decay[d]);
    float u = first[d];
    float aa = 0.f, bb = 0.f, pp = -1e38f;
    size_t base = (size_t)b * 1024 * 512 + d;
    float kc[4], vc[4], rc[4];
#pragma unroll
    for (int j = 0; j < 4; j++) {
        kc[j] = kbuf[base + (size_t)j * 512];
        vc[j] = vbuf[base + (size_t)j * 512];
        rc[j] = rbuf[base + (size_t)j * 512];
    }
    for (int t = 0; t < 1024; t += 4) {
        float kn[4] = {0, 0, 0, 0}, vn[4] = {0, 0, 0, 0}, rn[4] = {0, 0, 0, 0};
        if (t + 4 < 1024) {
            size_t nb = base + (size_t)(t + 4) * 512;
#pragma unroll
            for (int j = 0; j < 4; j++) {
                kn[j] = kbuf[nb + (size_t)j * 512];
                vn[j] = vbuf[nb + (size_t)j * 512];
                rn[j] = rbuf[nb + (size_t)j * 512];
            }
        }
#pragma unroll
        for (int j = 0; j < 4; j++) {
            float kt = kc[j], vt = vc[j], rt = rc[j];
            float ww = u + kt;
            float p = pp > ww ? pp : ww;
            float e1 = __expf(pp - p), e2 = __expf(ww - p);
            float out = (e1 * aa + e2 * vt) / (e1 * bb + e2);
            outbuf[base + (size_t)(t + j) * 512] = __float2bfloat16(rt * out);
            float ww2 = pp + w;
            float p2 = ww2 > kt ? ww2 : kt;
            e1 = __expf(ww2 - p2);
            e2 = __expf(kt - p2);
            aa = e1 * aa + e2 * vt;
            bb = e1 * bb + e2;
            pp = p2;
        }
#pragma unroll
        for (int j = 0; j < 4; j++) { kc[j] = kn[j]; vc[j] = vn[j]; rc[j] = rn[j]; }
    }
}

__global__ void olens_k(const int* __restrict__ x_len, float* __restrict__ out)
{
    int i = threadIdx.x;
    if (i < 8) {
        int l1 = (x_len[i] - 1) / 2 + 1;
        int ol = (l1 - 1) / 2 + 1;
        out[i] = (float)ol;
    }
}

// ---------------------------------------------------------------------------
extern "C" void kernel_launch(void* const* d_in, const int* in_sizes, int n_in,
                              void* d_out, int out_size, void* d_ws, size_t ws_size,
                              hipStream_t stream)
{
    (void)in_sizes; (void)n_in; (void)out_size; (void)ws_size;
    const float* x         = (const float*)d_in[0];
    const int*   x_len     = (const int*)d_in[1];
    const float* conv1_w   = (const float*)d_in[2];
    const float* conv1_b   = (const float*)d_in[3];
    const float* conv2_w   = (const float*)d_in[4];
    const float* conv2_b   = (const float*)d_in[5];
    const float* conv3_w   = (const float*)d_in[6];
    const float* conv3_b   = (const float*)d_in[7];
    const float* embed_w   = (const float*)d_in[8];
    const float* embed_b   = (const float*)d_in[9];
    const float* embed_ln_g= (const float*)d_in[10];
    const float* embed_ln_b= (const float*)d_in[11];
    const float* ln_att_g  = (const float*)d_in[12];
    const float* ln_att_b  = (const float*)d_in[13];
    const float* att_decay = (const float*)d_in[14];
    const float* att_first = (const float*)d_in[15];
    const float* att_mix_k = (const float*)d_in[16];
    const float* att_mix_v = (const float*)d_in[17];
    const float* att_mix_r = (const float*)d_in[18];
    const float* att_wk    = (const float*)d_in[19];
    const float* att_wv    = (const float*)d_in[20];
    const float* att_wr    = (const float*)d_in[21];
    const float* att_wo    = (const float*)d_in[22];
    const float* ln_ffn_g  = (const float*)d_in[23];
    const float* ln_ffn_b  = (const float*)d_in[24];
    const float* ffn_mix_k = (const float*)d_in[25];
    const float* ffn_mix_r = (const float*)d_in[26];
    const float* ffn_wk    = (const float*)d_in[27];
    const float* ffn_wv    = (const float*)d_in[28];
    const float* ffn_wr    = (const float*)d_in[29];
    const float* final_ln_g= (const float*)d_in[30];
    const float* final_ln_b= (const float*)d_in[31];

    // ---- workspace layout (MiB offsets, ~183 MiB) ----
    // 0..16 h | 16..32 xn | 32..40 rwkvb | 40..64 xkvr (xf aliases 40..56)
    // 64..112 kvrb | 112..144 kkb
    // conv overlay: c1b 40..80 | c2b(halo) 80..102.1 | c3b 104..144
    // weights: attT 144..150 | attTo 150..152 | ffnT 152..162 | ffnTv 162..170
    //          embT 170..180 | c2wb 180..180.6 | c3wb 180.6..182.9
    char* wsb = (char*)d_ws;
    float* h     = (float*)(wsb);
    float* xn    = (float*)(wsb + (16LL << 20));
    bf16*  rwkvb = (bf16*) (wsb + (32LL << 20));
    bf16*  xkvr  = (bf16*) (wsb + (40LL << 20));   // [3][8192][512] bf16
    bf16*  xf    = xkvr;                           // [2][8192][512] bf16 (ffn)
    float* kvrb  = (float*)(wsb + (64LL << 20));   // [3][8192][512] f32
    bf16*  kkb   = (bf16*) (wsb + (112LL << 20));  // [8192][2048] bf16
    bf16*  c1b   = (bf16*) (wsb + (40LL << 20));   // (2,2048,40,128)
    bf16*  c2b   = (bf16*) (wsb + (80LL << 20));   // (2,1026,22,256) halo
    bf16*  c3b   = (bf16*) (wsb + (104LL << 20));  // (2048,10240)
    bf16*  attT  = (bf16*) (wsb + (144LL << 20));  // 4 x [1536][512] (k,v,r)
    bf16*  attTo = (bf16*) (wsb + (150LL << 20));  // 4 x [512][512]  (wo)
    bf16*  ffnT  = (bf16*) (wsb + (152LL << 20));  // 4 x [2560][512] (wk|wr)
    bf16*  ffnTv = (bf16*) (wsb + (162LL << 20));  // 4 x [512][2048]
    bf16*  embT  = (bf16*) (wsb + (170LL << 20));  // [512][10240]
    bf16*  c2wb  = (bf16*) (wsb + (180LL << 20));  // 256 x 1152
    bf16*  c3wb  = (bf16*) (wsb + (180LL << 20) + 589824);  // 512 x 2304

    const size_t MD = 8192LL * 512;

    // ---- weight prep: packed transposed bf16
    transpose_k<<<dim3(16, 16, 4), 256, 0, stream>>>(att_wk, attT, 512, 512, 786432);
    transpose_k<<<dim3(16, 16, 4), 256, 0, stream>>>(att_wv, attT + 262144, 512, 512, 786432);
    transpose_k<<<dim3(16, 16, 4), 256, 0, stream>>>(att_wr, attT + 524288, 512, 512, 786432);
    transpose_k<<<dim3(16, 16, 4), 256, 0, stream>>>(att_wo, attTo, 512, 512, 262144);
    transpose_k<<<dim3(64, 16, 4), 256, 0, stream>>>(ffn_wk, ffnT, 512, 2048, 1310720);
    transpose_k<<<dim3(16, 16, 4), 256, 0, stream>>>(ffn_wr, ffnT + 1048576, 512, 512, 1310720);
    transpose_k<<<dim3(16, 64, 4), 256, 0, stream>>>(ffn_wv, ffnTv, 2048, 512, 1048576);
    transpose_k<<<dim3(16, 320, 1), 256, 0, stream>>>(embed_w, embT, 10240, 512, 0);
    reorder_w_k<<<1152, 256, 0, stream>>>(conv2_w, c2wb, 256, 128);
    reorder_w_k<<<4608, 256, 0, stream>>>(conv3_w, c3wb, 512, 256);
    hipMemsetAsync(xn, 0, 16LL << 20, stream);
    hipMemsetAsync(c2b, 0, 2LL * 1026 * 22 * 256 * 2, stream);

    // ---- conv frontend + embed (split-K x4, atomic), 2 batches per chunk
    for (int chunk = 0; chunk < 4; chunk++) {
        int b0 = chunk * 2;
        conv1_k<<<640, 256, 0, stream>>>(x + (size_t)b0 * 327680, conv1_w, conv1_b, c1b);
        gemm_k<128, B_CONV, EP_CONV_CL, 0, 2048, 40, 2, 128, 0><<<dim3(320, 2), 256, 0, stream>>>(
            c2wb, nullptr, c1b, nullptr, c2b, conv2_b, nullptr, 256, 40960, 1152, 1152);
        gemm_k<128, B_CONV, EP_CONV_T, 0, 1024, 20, 1, 256, 1><<<dim3(320, 4), 256, 0, stream>>>(
            c3wb, nullptr, c2b, nullptr, c3b, conv3_b, nullptr, 512, 40960, 2304, 2304);
        gemm_k<64, B_T, EP_ATOMIC, 0, 0, 0, 0, 0, 0><<<dim3(4, 32, 4), 256, 0, stream>>>(
            c3b, embT, nullptr, xn + (size_t)b0 * 1024 * 512, nullptr, embed_b, nullptr,
            2048, 512, 10240, 2560);
    }
    ln_k<<<2048, 256, 0, stream>>>(xn, h, embed_ln_g, embed_ln_b, 8192);

    // ---- 4 RWKV blocks
    for (int i = 0; i < 4; i++) {
        // time mixing (LN fused into mix)
        lnmix_k<3><<<2048, 256, 0, stream>>>(h, ln_att_g + i * 512, ln_att_b + i * 512,
                                             att_mix_k + i * 512, att_mix_v + i * 512,
                                             att_mix_r + i * 512,
                                             xkvr, xkvr + MD, xkvr + 2 * MD);
        gemm_k<64, B_T, EP_KVR, 9, 0, 0, 0, 0, 0><<<dim3(12, 128), 256, 0, stream>>>(
            xkvr, attT + (size_t)i * 786432, nullptr, kvrb, nullptr, nullptr, nullptr,
            8192, 1536, 512, 512);
        wkv_k<<<64, 64, 0, stream>>>(kvrb, kvrb + MD, kvrb + 2 * MD, rwkvb,
                                     att_decay + i * 512, att_first + i * 512);
        gemm_k<64, B_T, EP_ADD, 0, 0, 0, 0, 0, 0><<<dim3(4, 128), 256, 0, stream>>>(
            rwkvb, attTo + (size_t)i * 262144, nullptr, h, nullptr, nullptr, nullptr,
            8192, 512, 512, 512);
        // channel mixing (LN fused into mix)
        lnmix_k<2><<<2048, 256, 0, stream>>>(h, ln_ffn_g + i * 512, ln_ffn_b + i * 512,
                                             ffn_mix_k + i * 512, nullptr,
                                             ffn_mix_r + i * 512,
                                             xf, nullptr, xf + MD);
        gemm_k<64, B_T, EP_FFN, 11, 0, 0, 0, 0, 0><<<dim3(20, 128), 256, 0, stream>>>(
            xf, ffnT + (size_t)i * 1310720, nullptr, kvrb + 2 * MD, kkb, nullptr, nullptr,
            8192, 2560, 512, 512);
        gemm_k<64, B_T, EP_ADDMUL, 0, 0, 0, 0, 0, 0><<<dim3(4, 128), 256, 0, stream>>>(
            kkb, ffnTv + (size_t)i * 1048576, nullptr, h, nullptr, nullptr, kvrb + 2 * MD,
            8192, 512, 2048, 2048);
    }

    // ---- final LN straight into d_out, then olens
    ln_k<<<2048, 256, 0, stream>>>(h, (float*)d_out, final_ln_g, final_ln_b, 8192);
    olens_k<<<1, 64, 0, stream>>>(x_len, (float*)d_out + 4194304);
}